// Round 2
// baseline (1792.502 us; speedup 1.0000x reference)
//
#include <hip/hip_runtime.h>
#include <hip/hip_bf16.h>

typedef float f32x4 __attribute__((ext_vector_type(4)));
typedef short bf16x8 __attribute__((ext_vector_type(8)));
typedef unsigned short u16;

// ---------- helpers ----------

__device__ __forceinline__ void gload_lds16(const void* g, void* l) {
  __builtin_amdgcn_global_load_lds(
      (const __attribute__((address_space(1))) unsigned int*)g,
      (__attribute__((address_space(3))) unsigned int*)l, 16, 0, 0);
}

// round-to-nearest-even f32 -> bf16 bits (inputs here are exact small ints)
__device__ __forceinline__ u16 f2bf(float f) {
  unsigned u = __builtin_bit_cast(unsigned, f);
  u += 0x7fffu + ((u >> 16) & 1u);
  return (u16)(u >> 16);
}

__device__ __forceinline__ float wmean_clip(const double* p, double cnt) {
  double m = *p / cnt;
  if (m < 1e-5) m = 1e-5;
  return (float)m;
}

__device__ __forceinline__ float blk_sum(float v, float* s4) {
  for (int m = 32; m; m >>= 1) v += __shfl_xor(v, m);
  if ((threadIdx.x & 63) == 0) s4[threadIdx.x >> 6] = v;
  __syncthreads();
  float r = s4[0] + s4[1] + s4[2] + s4[3];
  __syncthreads();
  return r;
}

__device__ __forceinline__ float blk_max(float v, float* s4) {
  for (int m = 32; m; m >>= 1) v = fmaxf(v, __shfl_xor(v, m));
  if ((threadIdx.x & 63) == 0) s4[threadIdx.x >> 6] = v;
  __syncthreads();
  float r = fmaxf(fmaxf(s4[0], s4[1]), fmaxf(s4[2], s4[3]));
  __syncthreads();
  return r;
}

// ---------- weight mean-abs reduction (fp64 accumulate) ----------

__global__ __launch_bounds__(256) void wabs_reduce(
    const float* __restrict__ W, size_t n4, double* __restrict__ out) {
  __shared__ double s4[4];
  const float4* W4 = (const float4*)W;
  size_t i = (size_t)blockIdx.x * 256 + threadIdx.x;
  size_t stride = (size_t)gridDim.x * 256;
  double s = 0.0;
  for (; i < n4; i += stride) {
    float4 v = W4[i];
    s += (double)fabsf(v.x);
    s += (double)fabsf(v.y);
    s += (double)fabsf(v.z);
    s += (double)fabsf(v.w);
  }
  for (int m = 32; m; m >>= 1) s += __shfl_xor(s, m);
  if ((threadIdx.x & 63) == 0) s4[threadIdx.x >> 6] = s;
  __syncthreads();
  if (threadIdx.x == 0) atomicAdd(out, s4[0] + s4[1] + s4[2] + s4[3]);
}

// ---------- weight ternary quant: store t in {-1,0,1} as bf16 ----------

__global__ __launch_bounds__(256) void wquant(
    const float* __restrict__ W, u16* __restrict__ Wq, size_t n4,
    const double* __restrict__ sum, double cnt) {
  float cm = wmean_clip(sum, cnt);
  float scale = 1.0f / cm;
  const float4* W4 = (const float4*)W;
  size_t i = (size_t)blockIdx.x * 256 + threadIdx.x;
  size_t stride = (size_t)gridDim.x * 256;
  for (; i < n4; i += stride) {
    float4 v = W4[i];
    ushort4 o;
    o.x = f2bf(fminf(fmaxf(rintf(v.x * scale), -1.f), 1.f));
    o.y = f2bf(fminf(fmaxf(rintf(v.y * scale), -1.f), 1.f));
    o.z = f2bf(fminf(fmaxf(rintf(v.z * scale), -1.f), 1.f));
    o.w = f2bf(fminf(fmaxf(rintf(v.w * scale), -1.f), 1.f));
    *(ushort4*)&Wq[i * 4] = o;
  }
}

// ---------- per-row RMSNorm + int8 act quant (bf16 integer output) ----------
// PLAIN: xn = x * rsqrt(mean(x^2)+1e-8)
// HEAD : z = x * rsqrt(mean(x^2)+eps1) * nw ; xn = z * rsqrt(mean(z^2)+1e-8)
// then: cs = max(absmax(xn),1e-5); q = clamp(rint(xn*127/cs),-128,127)
// store q as bf16 (exact), rowscale = cs/127.

template <bool HEAD>
__global__ __launch_bounds__(256) void rowquant(
    const float* __restrict__ X, const float* __restrict__ nw,
    u16* __restrict__ Aq, float* __restrict__ rowscale, float eps1) {
  __shared__ float s4[4];
  const int t = threadIdx.x;
  const size_t base = (size_t)blockIdx.x * 4096;
  float x[16];
#pragma unroll
  for (int c = 0; c < 4; ++c) {
    float4 v = *(const float4*)&X[base + c * 1024 + t * 4];
    x[c * 4 + 0] = v.x; x[c * 4 + 1] = v.y;
    x[c * 4 + 2] = v.z; x[c * 4 + 3] = v.w;
  }
  float ss = 0.f;
#pragma unroll
  for (int i = 0; i < 16; ++i) ss += x[i] * x[i];
  ss = blk_sum(ss, s4);
  float inv = 1.0f / sqrtf(ss * (1.0f / 4096.0f) + eps1);
  if (HEAD) {
#pragma unroll
    for (int c = 0; c < 4; ++c) {
      float4 w = *(const float4*)&nw[c * 1024 + t * 4];
      x[c * 4 + 0] = x[c * 4 + 0] * inv * w.x;
      x[c * 4 + 1] = x[c * 4 + 1] * inv * w.y;
      x[c * 4 + 2] = x[c * 4 + 2] * inv * w.z;
      x[c * 4 + 3] = x[c * 4 + 3] * inv * w.w;
    }
    float ss2 = 0.f;
#pragma unroll
    for (int i = 0; i < 16; ++i) ss2 += x[i] * x[i];
    ss2 = blk_sum(ss2, s4);
    inv = 1.0f / sqrtf(ss2 * (1.0f / 4096.0f) + 1e-8f);
  }
#pragma unroll
  for (int i = 0; i < 16; ++i) x[i] = x[i] * inv;  // xn
  float amax = 0.f;
#pragma unroll
  for (int i = 0; i < 16; ++i) amax = fmaxf(amax, fabsf(x[i]));
  amax = blk_max(amax, s4);
  float cs = fmaxf(amax, 1e-5f);
  float sx = 127.0f / cs;
#pragma unroll
  for (int c = 0; c < 4; ++c) {
    ushort4 o;
    float q0 = fminf(fmaxf(rintf(x[c * 4 + 0] * sx), -128.f), 127.f);
    float q1 = fminf(fmaxf(rintf(x[c * 4 + 1] * sx), -128.f), 127.f);
    float q2 = fminf(fmaxf(rintf(x[c * 4 + 2] * sx), -128.f), 127.f);
    float q3 = fminf(fmaxf(rintf(x[c * 4 + 3] * sx), -128.f), 127.f);
    o.x = f2bf(q0); o.y = f2bf(q1); o.z = f2bf(q2); o.w = f2bf(q3);
    *(ushort4*)&Aq[base + c * 1024 + t * 4] = o;
  }
  if (t == 0) rowscale[blockIdx.x] = cs / 127.0f;
}

// ---------- GEMM1: C tiles for gate and v halves + fused swiglu ----------
// A: [M][4096] bf16(int), Wg: [8192][4096] bf16 ternary. Output SW fp32 [M][4096].
// BM=128, BN=64 (gate cols) + same 64 v cols (row+4096). 4 waves 2x2, wave=64x32 per set.

__global__ __launch_bounds__(256) void gemm1_fused(
    const u16* __restrict__ A, const u16* __restrict__ Wg,
    float* __restrict__ SW, const float* __restrict__ rowscale,
    const double* __restrict__ wsum) {
  const int K = 4096;
  __shared__ u16 As[128 * 32];
  __shared__ u16 Bg[64 * 32];
  __shared__ u16 Bv[64 * 32];
  const int t = threadIdx.x;
  const int bm0 = blockIdx.y * 128;
  const int bn0 = blockIdx.x * 64;
  const int lane = t & 63, wave = t >> 6;
  const int wr = wave >> 1, wc = wave & 1;

  f32x4 accg[4][2] = {};
  f32x4 accv[4][2] = {};

  const int srow = t >> 2, scol = (t & 3) * 8;
  const u16* ga0 = A + (size_t)(bm0 + srow) * K + scol;
  const u16* ga1 = ga0 + (size_t)64 * K;
  const u16* gg = Wg + (size_t)(bn0 + srow) * K + scol;
  const u16* gv = Wg + (size_t)(4096 + bn0 + srow) * K + scol;
  u16* lA0 = As + t * 8;
  u16* lA1 = As + 2048 + t * 8;
  u16* lG = Bg + t * 8;
  u16* lV = Bv + t * 8;

  for (int kt = 0; kt < K; kt += 32) {
    gload_lds16(ga0 + kt, lA0);
    gload_lds16(ga1 + kt, lA1);
    gload_lds16(gg + kt, lG);
    gload_lds16(gv + kt, lV);
    __syncthreads();
    const int ar = wr * 64 + (lane & 15);
    const int br = wc * 32 + (lane & 15);
    const int ch = (lane >> 4) * 8;
    bf16x8 af[4], bg[2], bv[2];
#pragma unroll
    for (int m = 0; m < 4; ++m) af[m] = *(const bf16x8*)&As[(ar + m * 16) * 32 + ch];
#pragma unroll
    for (int n = 0; n < 2; ++n) {
      bg[n] = *(const bf16x8*)&Bg[(br + n * 16) * 32 + ch];
      bv[n] = *(const bf16x8*)&Bv[(br + n * 16) * 32 + ch];
    }
#pragma unroll
    for (int m = 0; m < 4; ++m)
#pragma unroll
      for (int n = 0; n < 2; ++n) {
        accg[m][n] = __builtin_amdgcn_mfma_f32_16x16x32_bf16(af[m], bg[n], accg[m][n], 0, 0, 0);
        accv[m][n] = __builtin_amdgcn_mfma_f32_16x16x32_bf16(af[m], bv[n], accv[m][n], 0, 0, 0);
      }
    __syncthreads();
  }

  const float cm = wmean_clip(wsum, 33554432.0);
#pragma unroll
  for (int m = 0; m < 4; ++m) {
    const int r0 = bm0 + wr * 64 + m * 16 + (lane >> 4) * 4;
#pragma unroll
    for (int j = 0; j < 4; ++j) {
      const int row = r0 + j;
      const float f = rowscale[row] * cm;
#pragma unroll
      for (int n = 0; n < 2; ++n) {
        const int col = bn0 + wc * 32 + n * 16 + (lane & 15);
        float g = accg[m][n][j] * f;
        float v = accv[m][n][j] * f;
        float s = g / (1.0f + expf(-g)) * v;  // swiglu
        SW[(size_t)row * 4096 + col] = s;
      }
    }
  }
}

// ---------- GEMM2/3: 128x128 tile, B^T layout ----------
// EPI 0: C[M][4096] = acc*scale.  EPI 1: split cols <2048 -> scale, >=2048 -> shift.

template <int EPI>
__global__ __launch_bounds__(256) void gemm_bt(
    const u16* __restrict__ A, const u16* __restrict__ B,
    float* __restrict__ C, const float* __restrict__ rowscale,
    const double* __restrict__ wsum, double wcnt, int M) {
  const int K = 4096, N = 4096;
  __shared__ u16 As[128 * 32];
  __shared__ u16 Bs[128 * 32];
  const int t = threadIdx.x;
  const int bm0 = blockIdx.y * 128, bn0 = blockIdx.x * 128;
  const int lane = t & 63, wave = t >> 6;
  const int wr = wave >> 1, wc = wave & 1;

  f32x4 acc[4][4] = {};

  const int srow = t >> 2, scol = (t & 3) * 8;
  const u16* gA0 = A + (size_t)(bm0 + srow) * K + scol;
  const u16* gA1 = gA0 + (size_t)64 * K;
  const u16* gB0 = B + (size_t)(bn0 + srow) * K + scol;
  const u16* gB1 = gB0 + (size_t)64 * K;
  u16* lA0 = As + t * 8;
  u16* lA1 = As + 2048 + t * 8;
  u16* lB0 = Bs + t * 8;
  u16* lB1 = Bs + 2048 + t * 8;

  for (int kt = 0; kt < K; kt += 32) {
    gload_lds16(gA0 + kt, lA0);
    gload_lds16(gA1 + kt, lA1);
    gload_lds16(gB0 + kt, lB0);
    gload_lds16(gB1 + kt, lB1);
    __syncthreads();
    const int ar = wr * 64 + (lane & 15);
    const int br = wc * 64 + (lane & 15);
    const int ch = (lane >> 4) * 8;
    bf16x8 af[4], bf[4];
#pragma unroll
    for (int m = 0; m < 4; ++m) af[m] = *(const bf16x8*)&As[(ar + m * 16) * 32 + ch];
#pragma unroll
    for (int n = 0; n < 4; ++n) bf[n] = *(const bf16x8*)&Bs[(br + n * 16) * 32 + ch];
#pragma unroll
    for (int m = 0; m < 4; ++m)
#pragma unroll
      for (int n = 0; n < 4; ++n)
        acc[m][n] = __builtin_amdgcn_mfma_f32_16x16x32_bf16(af[m], bf[n], acc[m][n], 0, 0, 0);
    __syncthreads();
  }

  const float cm = wmean_clip(wsum, wcnt);
#pragma unroll
  for (int m = 0; m < 4; ++m) {
    const int r0 = bm0 + wr * 64 + m * 16 + (lane >> 4) * 4;
#pragma unroll
    for (int j = 0; j < 4; ++j) {
      const int row = r0 + j;
      const float f = rowscale[row] * cm;
#pragma unroll
      for (int n = 0; n < 4; ++n) {
        const int col = bn0 + wc * 64 + n * 16 + (lane & 15);
        const float val = acc[m][n][j] * f;
        if (EPI == 0) {
          C[(size_t)row * N + col] = val;
        } else {
          if (col < 2048)
            C[(size_t)row * 2048 + col] = val;
          else
            C[(size_t)M * 2048 + (size_t)row * 2048 + (col - 2048)] = val;
        }
      }
    }
  }
}

// ---------- launch ----------

extern "C" void kernel_launch(void* const* d_in, const int* in_sizes, int n_in,
                              void* d_out, int out_size, void* d_ws, size_t ws_size,
                              hipStream_t stream) {
  const float* cond = (const float*)d_in[0];     // [M][4096]
  const float* w_gate = (const float*)d_in[1];   // [8192][4096]
  const float* w_down = (const float*)d_in[2];   // [4096][4096]
  const float* norm_w = (const float*)d_in[3];   // [4096]
  const float* w_out = (const float*)d_in[4];    // [4096][4096]
  float* out = (float*)d_out;

  const int M = in_sizes[0] / 4096;  // 8192 tokens

  // workspace layout (~336 MB)
  char* ws = (char*)d_ws;
  double* sums = (double*)ws;                                   // 3 doubles
  u16* wq_gate = (u16*)(ws + 256);                              // 67,108,864 B
  u16* wq_down = wq_gate + (size_t)8192 * 4096;                 // 33,554,432 B
  u16* wq_out = wq_down + (size_t)4096 * 4096;                  // 33,554,432 B
  u16* Aq = wq_out + (size_t)4096 * 4096;                       // M*4096*2 B
  float* rowscale = (float*)(Aq + (size_t)M * 4096);            // M floats
  float* act = rowscale + 8192;                                 // M*4096*4 B

  hipMemsetAsync(sums, 0, 3 * sizeof(double), stream);

  // weight scales (mean |w|, fp64 accumulate)
  wabs_reduce<<<1024, 256, 0, stream>>>(w_gate, (size_t)8192 * 4096 / 4, &sums[0]);
  wabs_reduce<<<1024, 256, 0, stream>>>(w_down, (size_t)4096 * 4096 / 4, &sums[1]);
  wabs_reduce<<<1024, 256, 0, stream>>>(w_out, (size_t)4096 * 4096 / 4, &sums[2]);

  // ternary weight quant
  wquant<<<2048, 256, 0, stream>>>(w_gate, wq_gate, (size_t)8192 * 4096 / 4, &sums[0], 33554432.0);
  wquant<<<2048, 256, 0, stream>>>(w_down, wq_down, (size_t)4096 * 4096 / 4, &sums[1], 16777216.0);
  wquant<<<2048, 256, 0, stream>>>(w_out, wq_out, (size_t)4096 * 4096 / 4, &sums[2], 16777216.0);

  // layer 1: rmsnorm+quant(condition) -> fused gate/v GEMM + swiglu -> act
  rowquant<false><<<M, 256, 0, stream>>>(cond, nullptr, Aq, rowscale, 1e-8f);
  gemm1_fused<<<dim3(4096 / 64, M / 128), 256, 0, stream>>>(Aq, wq_gate, act, rowscale, &sums[0]);

  // layer 2: rmsnorm+quant(swiglu) -> GEMM -> act (h)
  rowquant<false><<<M, 256, 0, stream>>>(act, nullptr, Aq, rowscale, 1e-8f);
  gemm_bt<0><<<dim3(4096 / 128, M / 128), 256, 0, stream>>>(Aq, wq_down, act, rowscale, &sums[1], 16777216.0, M);

  // head: weighted rmsnorm (1e-6) + internal rmsnorm (1e-8) + quant -> GEMM -> split out
  rowquant<true><<<M, 256, 0, stream>>>(act, norm_w, Aq, rowscale, 1e-6f);
  gemm_bt<1><<<dim3(4096 / 128, M / 128), 256, 0, stream>>>(Aq, wq_out, out, rowscale, &sums[2], 16777216.0, M);
}

// Round 4
// 1629.711 us; speedup vs baseline: 1.0999x; 1.0999x over previous
//
#include <hip/hip_runtime.h>
#include <hip/hip_bf16.h>

typedef int i32x4 __attribute__((ext_vector_type(4)));
typedef signed char i8;

// ---------- helpers ----------

__device__ __forceinline__ void gload_lds16(const void* g, void* l) {
  __builtin_amdgcn_global_load_lds(
      (const __attribute__((address_space(1))) unsigned int*)g,
      (__attribute__((address_space(3))) unsigned int*)l, 16, 0, 0);
}

__device__ __forceinline__ float wmean_clip(const double* p, double cnt) {
  double m = *p / cnt;
  if (m < 1e-5) m = 1e-5;
  return (float)m;
}

__device__ __forceinline__ float blk_sum(float v, float* s4) {
  for (int m = 32; m; m >>= 1) v += __shfl_xor(v, m);
  if ((threadIdx.x & 63) == 0) s4[threadIdx.x >> 6] = v;
  __syncthreads();
  float r = s4[0] + s4[1] + s4[2] + s4[3];
  __syncthreads();
  return r;
}

__device__ __forceinline__ float blk_max(float v, float* s4) {
  for (int m = 32; m; m >>= 1) v = fmaxf(v, __shfl_xor(v, m));
  if ((threadIdx.x & 63) == 0) s4[threadIdx.x >> 6] = v;
  __syncthreads();
  float r = fmaxf(fmaxf(s4[0], s4[1]), fmaxf(s4[2], s4[3]));
  __syncthreads();
  return r;
}

// bijective XCD-aware block swizzle (nwg divisible by 8)
__device__ __forceinline__ void xcd_swz(int gx, int& bm, int& bn) {
  const int nwg = gx * gridDim.y;
  const int o = blockIdx.y * gx + blockIdx.x;
  const int s = (o & 7) * (nwg >> 3) + (o >> 3);
  bm = s / gx;
  bn = s % gx;
}

// ---------- weight mean-abs reduction (fp64 accumulate) ----------

__global__ __launch_bounds__(256) void wabs_reduce(
    const float* __restrict__ W, size_t n4, double* __restrict__ out) {
  __shared__ double s4[4];
  const float4* W4 = (const float4*)W;
  size_t i = (size_t)blockIdx.x * 256 + threadIdx.x;
  size_t stride = (size_t)gridDim.x * 256;
  double s = 0.0;
  for (; i < n4; i += stride) {
    float4 v = W4[i];
    s += (double)fabsf(v.x);
    s += (double)fabsf(v.y);
    s += (double)fabsf(v.z);
    s += (double)fabsf(v.w);
  }
  for (int m = 32; m; m >>= 1) s += __shfl_xor(s, m);
  if ((threadIdx.x & 63) == 0) s4[threadIdx.x >> 6] = s;
  __syncthreads();
  if (threadIdx.x == 0) atomicAdd(out, s4[0] + s4[1] + s4[2] + s4[3]);
}

// ---------- weight ternary quant -> i8 {-1,0,1} ----------

__global__ __launch_bounds__(256) void wquant(
    const float* __restrict__ W, i8* __restrict__ Wq, size_t n4,
    const double* __restrict__ sum, double cnt) {
  float cm = wmean_clip(sum, cnt);
  float scale = 1.0f / cm;
  const float4* W4 = (const float4*)W;
  size_t i = (size_t)blockIdx.x * 256 + threadIdx.x;
  size_t stride = (size_t)gridDim.x * 256;
  for (; i < n4; i += stride) {
    float4 v = W4[i];
    char4 o;
    o.x = (i8)fminf(fmaxf(rintf(v.x * scale), -1.f), 1.f);
    o.y = (i8)fminf(fmaxf(rintf(v.y * scale), -1.f), 1.f);
    o.z = (i8)fminf(fmaxf(rintf(v.z * scale), -1.f), 1.f);
    o.w = (i8)fminf(fmaxf(rintf(v.w * scale), -1.f), 1.f);
    *(char4*)&Wq[i * 4] = o;
  }
}

// ---------- per-row RMSNorm + int8 act quant -> i8 ----------
// PLAIN: xn = x * rsqrt(mean(x^2)+1e-8)
// HEAD : z = x * rsqrt(mean(x^2)+eps1) * nw ; xn = z * rsqrt(mean(z^2)+1e-8)
// then: cs = max(absmax(xn),1e-5); q = clamp(rint(xn*127/cs),-128,127)
// store q as i8, rowscale = cs/127.

template <bool HEAD>
__global__ __launch_bounds__(256) void rowquant(
    const float* __restrict__ X, const float* __restrict__ nw,
    i8* __restrict__ Aq, float* __restrict__ rowscale, float eps1) {
  __shared__ float s4[4];
  const int t = threadIdx.x;
  const size_t base = (size_t)blockIdx.x * 4096;
  float x[16];
#pragma unroll
  for (int c = 0; c < 4; ++c) {
    float4 v = *(const float4*)&X[base + c * 1024 + t * 4];
    x[c * 4 + 0] = v.x; x[c * 4 + 1] = v.y;
    x[c * 4 + 2] = v.z; x[c * 4 + 3] = v.w;
  }
  float ss = 0.f;
#pragma unroll
  for (int i = 0; i < 16; ++i) ss += x[i] * x[i];
  ss = blk_sum(ss, s4);
  float inv = 1.0f / sqrtf(ss * (1.0f / 4096.0f) + eps1);
  if (HEAD) {
#pragma unroll
    for (int c = 0; c < 4; ++c) {
      float4 w = *(const float4*)&nw[c * 1024 + t * 4];
      x[c * 4 + 0] = x[c * 4 + 0] * inv * w.x;
      x[c * 4 + 1] = x[c * 4 + 1] * inv * w.y;
      x[c * 4 + 2] = x[c * 4 + 2] * inv * w.z;
      x[c * 4 + 3] = x[c * 4 + 3] * inv * w.w;
    }
    float ss2 = 0.f;
#pragma unroll
    for (int i = 0; i < 16; ++i) ss2 += x[i] * x[i];
    ss2 = blk_sum(ss2, s4);
    inv = 1.0f / sqrtf(ss2 * (1.0f / 4096.0f) + 1e-8f);
  }
#pragma unroll
  for (int i = 0; i < 16; ++i) x[i] = x[i] * inv;  // xn
  float amax = 0.f;
#pragma unroll
  for (int i = 0; i < 16; ++i) amax = fmaxf(amax, fabsf(x[i]));
  amax = blk_max(amax, s4);
  float cs = fmaxf(amax, 1e-5f);
  float sx = 127.0f / cs;
#pragma unroll
  for (int c = 0; c < 4; ++c) {
    char4 o;
    o.x = (i8)fminf(fmaxf(rintf(x[c * 4 + 0] * sx), -128.f), 127.f);
    o.y = (i8)fminf(fmaxf(rintf(x[c * 4 + 1] * sx), -128.f), 127.f);
    o.z = (i8)fminf(fmaxf(rintf(x[c * 4 + 2] * sx), -128.f), 127.f);
    o.w = (i8)fminf(fmaxf(rintf(x[c * 4 + 3] * sx), -128.f), 127.f);
    *(char4*)&Aq[base + c * 1024 + t * 4] = o;
  }
  if (t == 0) rowscale[blockIdx.x] = cs / 127.0f;
}

// ---------- GEMM1 (i8): gate+v tiles + fused swiglu ----------
// A: [M][4096] i8, Wg: [8192][4096] i8 ternary. Output SW fp32 [M][4096].
// BM=128, BN=64 gate cols + matching 64 v cols (row+4096).
// LDS k-chunk-major: tile[kchunk 4][row][16B] -> conflict-free b128 reads.

__global__ __launch_bounds__(256) void gemm1_fused(
    const i8* __restrict__ A, const i8* __restrict__ Wg,
    float* __restrict__ SW, const float* __restrict__ rowscale,
    const double* __restrict__ wsum) {
  const int K = 4096;
  __shared__ i8 As[8192];   // [4][128][16]
  __shared__ i8 Bg[4096];   // [4][64][16]
  __shared__ i8 Bv[4096];
  const int t = threadIdx.x;
  int bmi, bni;
  xcd_swz(64, bmi, bni);
  const int bm0 = bmi * 128, bn0 = bni * 64;
  const int lane = t & 63, wave = t >> 6;
  const int wr = wave >> 1, wc = wave & 1;

  i32x4 accg[4][2] = {};
  i32x4 accv[4][2] = {};

  // staging sources (pre-mapped for k-chunk-major LDS layout)
  const i8* gA = A + (size_t)(bm0 + (t & 127)) * K + (t >> 7) * 16;
  const i8* gG = Wg + (size_t)(bn0 + (t & 63)) * K + (t >> 6) * 16;
  const i8* gV = Wg + (size_t)(4096 + bn0 + (t & 63)) * K + (t >> 6) * 16;
  i8* lA0 = As + t * 16;
  i8* lA1 = As + 4096 + t * 16;
  i8* lG = Bg + t * 16;
  i8* lV = Bv + t * 16;

  for (int kt = 0; kt < K; kt += 64) {
    gload_lds16(gA + kt, lA0);
    gload_lds16(gA + kt + 32, lA1);
    gload_lds16(gG + kt, lG);
    gload_lds16(gV + kt, lV);
    __syncthreads();
    const int ar = wr * 64 + (lane & 15);
    const int br = wc * 32 + (lane & 15);
    const int kcA = (lane >> 4) * 2048;  // chunk base in As
    const int kcB = (lane >> 4) * 1024;  // chunk base in Bg/Bv
    i32x4 af[4], bg[2], bv[2];
#pragma unroll
    for (int m = 0; m < 4; ++m) af[m] = *(const i32x4*)&As[kcA + (ar + m * 16) * 16];
#pragma unroll
    for (int n = 0; n < 2; ++n) {
      bg[n] = *(const i32x4*)&Bg[kcB + (br + n * 16) * 16];
      bv[n] = *(const i32x4*)&Bv[kcB + (br + n * 16) * 16];
    }
#pragma unroll
    for (int m = 0; m < 4; ++m)
#pragma unroll
      for (int n = 0; n < 2; ++n) {
        accg[m][n] = __builtin_amdgcn_mfma_i32_16x16x64_i8(af[m], bg[n], accg[m][n], 0, 0, 0);
        accv[m][n] = __builtin_amdgcn_mfma_i32_16x16x64_i8(af[m], bv[n], accv[m][n], 0, 0, 0);
      }
    __syncthreads();
  }

  const float cm = wmean_clip(wsum, 33554432.0);
#pragma unroll
  for (int m = 0; m < 4; ++m) {
    const int r0 = bm0 + wr * 64 + m * 16 + (lane >> 4) * 4;
#pragma unroll
    for (int j = 0; j < 4; ++j) {
      const int row = r0 + j;
      const float f = rowscale[row] * cm;
#pragma unroll
      for (int n = 0; n < 2; ++n) {
        const int col = bn0 + wc * 32 + n * 16 + (lane & 15);
        float g = (float)accg[m][n][j] * f;
        float v = (float)accv[m][n][j] * f;
        float s = g / (1.0f + expf(-g)) * v;  // swiglu
        SW[(size_t)row * 4096 + col] = s;
      }
    }
  }
}

// ---------- GEMM2/3 (i8): 128x128 tile, B^T layout ----------
// EPI 0: C[M][4096] = acc*scale.  EPI 1: split cols <2048 -> scale, >=2048 -> shift.

template <int EPI>
__global__ __launch_bounds__(256) void gemm_bt(
    const i8* __restrict__ A, const i8* __restrict__ B,
    float* __restrict__ C, const float* __restrict__ rowscale,
    const double* __restrict__ wsum, double wcnt, int M) {
  const int K = 4096, N = 4096;
  __shared__ i8 As[8192];   // [4][128][16]
  __shared__ i8 Bs[8192];
  const int t = threadIdx.x;
  int bmi, bni;
  xcd_swz(32, bmi, bni);
  const int bm0 = bmi * 128, bn0 = bni * 128;
  const int lane = t & 63, wave = t >> 6;
  const int wr = wave >> 1, wc = wave & 1;

  i32x4 acc[4][4] = {};

  const i8* gA = A + (size_t)(bm0 + (t & 127)) * K + (t >> 7) * 16;
  const i8* gB = B + (size_t)(bn0 + (t & 127)) * K + (t >> 7) * 16;
  i8* lA0 = As + t * 16;
  i8* lA1 = As + 4096 + t * 16;
  i8* lB0 = Bs + t * 16;
  i8* lB1 = Bs + 4096 + t * 16;

  for (int kt = 0; kt < K; kt += 64) {
    gload_lds16(gA + kt, lA0);
    gload_lds16(gA + kt + 32, lA1);
    gload_lds16(gB + kt, lB0);
    gload_lds16(gB + kt + 32, lB1);
    __syncthreads();
    const int ar = wr * 64 + (lane & 15);
    const int br = wc * 64 + (lane & 15);
    const int kc = (lane >> 4) * 2048;
    i32x4 af[4], bfr[4];
#pragma unroll
    for (int m = 0; m < 4; ++m) af[m] = *(const i32x4*)&As[kc + (ar + m * 16) * 16];
#pragma unroll
    for (int n = 0; n < 4; ++n) bfr[n] = *(const i32x4*)&Bs[kc + (br + n * 16) * 16];
#pragma unroll
    for (int m = 0; m < 4; ++m)
#pragma unroll
      for (int n = 0; n < 4; ++n)
        acc[m][n] = __builtin_amdgcn_mfma_i32_16x16x64_i8(af[m], bfr[n], acc[m][n], 0, 0, 0);
    __syncthreads();
  }

  const float cm = wmean_clip(wsum, wcnt);
#pragma unroll
  for (int m = 0; m < 4; ++m) {
    const int r0 = bm0 + wr * 64 + m * 16 + (lane >> 4) * 4;
#pragma unroll
    for (int j = 0; j < 4; ++j) {
      const int row = r0 + j;
      const float f = rowscale[row] * cm;
#pragma unroll
      for (int n = 0; n < 4; ++n) {
        const int col = bn0 + wc * 64 + n * 16 + (lane & 15);
        const float val = (float)acc[m][n][j] * f;
        if (EPI == 0) {
          C[(size_t)row * N + col] = val;
        } else {
          if (col < 2048)
            C[(size_t)row * 2048 + col] = val;
          else
            C[(size_t)M * 2048 + (size_t)row * 2048 + (col - 2048)] = val;
        }
      }
    }
  }
}

// ---------- launch ----------

extern "C" void kernel_launch(void* const* d_in, const int* in_sizes, int n_in,
                              void* d_out, int out_size, void* d_ws, size_t ws_size,
                              hipStream_t stream) {
  const float* cond = (const float*)d_in[0];     // [M][4096]
  const float* w_gate = (const float*)d_in[1];   // [8192][4096]
  const float* w_down = (const float*)d_in[2];   // [4096][4096]
  const float* norm_w = (const float*)d_in[3];   // [4096]
  const float* w_out = (const float*)d_in[4];    // [4096][4096]
  float* out = (float*)d_out;

  const int M = in_sizes[0] / 4096;  // 8192 tokens

  // workspace layout (~235 MB)
  char* ws = (char*)d_ws;
  double* sums = (double*)ws;                                   // 3 doubles (256 B reserved)
  i8* wq_gate = (i8*)(ws + 256);                                // 33,554,432 B
  i8* wq_down = wq_gate + (size_t)8192 * 4096;                  // 16,777,216 B
  i8* wq_out = wq_down + (size_t)4096 * 4096;                   // 16,777,216 B
  i8* Aq = wq_out + (size_t)4096 * 4096;                        // M*4096 B
  float* rowscale = (float*)(Aq + (size_t)M * 4096);            // M floats
  float* act = rowscale + 8192;                                 // M*4096*4 B

  hipMemsetAsync(sums, 0, 3 * sizeof(double), stream);

  // weight scales (mean |w|, fp64 accumulate)
  wabs_reduce<<<1024, 256, 0, stream>>>(w_gate, (size_t)8192 * 4096 / 4, &sums[0]);
  wabs_reduce<<<1024, 256, 0, stream>>>(w_down, (size_t)4096 * 4096 / 4, &sums[1]);
  wabs_reduce<<<1024, 256, 0, stream>>>(w_out, (size_t)4096 * 4096 / 4, &sums[2]);

  // ternary weight quant -> i8
  wquant<<<2048, 256, 0, stream>>>(w_gate, wq_gate, (size_t)8192 * 4096 / 4, &sums[0], 33554432.0);
  wquant<<<2048, 256, 0, stream>>>(w_down, wq_down, (size_t)4096 * 4096 / 4, &sums[1], 16777216.0);
  wquant<<<2048, 256, 0, stream>>>(w_out, wq_out, (size_t)4096 * 4096 / 4, &sums[2], 16777216.0);

  // layer 1: rmsnorm+quant(condition) -> fused gate/v GEMM + swiglu -> act
  rowquant<false><<<M, 256, 0, stream>>>(cond, nullptr, Aq, rowscale, 1e-8f);
  gemm1_fused<<<dim3(4096 / 64, M / 128), 256, 0, stream>>>(Aq, wq_gate, act, rowscale, &sums[0]);

  // layer 2: rmsnorm+quant(swiglu) -> GEMM -> act (h)
  rowquant<false><<<M, 256, 0, stream>>>(act, nullptr, Aq, rowscale, 1e-8f);
  gemm_bt<0><<<dim3(4096 / 128, M / 128), 256, 0, stream>>>(Aq, wq_down, act, rowscale, &sums[1], 16777216.0, M);

  // head: weighted rmsnorm (1e-6) + internal rmsnorm (1e-8) + quant -> GEMM -> split out
  rowquant<true><<<M, 256, 0, stream>>>(act, norm_w, Aq, rowscale, 1e-6f);
  gemm_bt<1><<<dim3(4096 / 128, M / 128), 256, 0, stream>>>(Aq, wq_out, out, rowscale, &sums[2], 16777216.0, M);
}